// Round 5
// baseline (282.536 us; speedup 1.0000x reference)
//
#include <hip/hip_runtime.h>
#include <math.h>

#define NTH 256
#define LSEQ 2048
#define NF 4096
#define NH 512
#define NS 64
#define NB 8
#define NPAIR 256
#define ASTR 1040
#define TWO_PI 6.2831853071795864769f
// XOR swizzle: bijective, modifies only bits 0-3; spreads every FFT pass's
// lane pattern evenly over banks (4 dwords/bank = b64 natural minimum).
#define SW(i) ((i) ^ (((i) >> 4) & 15) ^ (((i) >> 8) & 15))
#define DR11(l) ((((l) & 15) << 7) | ((((l) >> 4) & 15) << 3) | ((l) >> 8))

#define C16_1 0.9238795325112867f
#define C16_2 0.7071067811865476f
#define C16_3 0.3826834323650898f

__device__ __forceinline__ float2 cmul(float2 a, float2 b) {
    return make_float2(a.x*b.x - a.y*b.y, a.x*b.y + a.y*b.x);
}
__device__ __forceinline__ float2 cmulw(float2 a, float wr, float wi) {
    return make_float2(a.x*wr - a.y*wi, a.x*wi + a.y*wr);
}

// ---- stages 2..4 of the 16-point DIF DFT (shared tail) ----
template<bool INV>
__device__ __forceinline__ void fft16_tail(float2* y) {
    const float sg = INV ? -1.f : 1.f;
    const float WR[8] = {1.f, C16_1, C16_2, C16_3, 0.f, -C16_3, -C16_2, -C16_1};
    const float WI[8] = {0.f, -C16_3, -C16_2, -C16_1, -1.f, -C16_1, -C16_2, -C16_3};
    #pragma unroll
    for (int h = 0; h < 16; h += 8)
        #pragma unroll
        for (int j = 0; j < 4; ++j) {
            float2 a = y[h+j], b = y[h+j+4];
            float2 d = make_float2(a.x-b.x, a.y-b.y);
            y[h+j] = make_float2(a.x+b.x, a.y+b.y);
            y[h+j+4] = cmulw(d, WR[2*j], sg*WI[2*j]);
        }
    #pragma unroll
    for (int h = 0; h < 16; h += 4)
        #pragma unroll
        for (int j = 0; j < 2; ++j) {
            float2 a = y[h+j], b = y[h+j+2];
            float2 d = make_float2(a.x-b.x, a.y-b.y);
            y[h+j] = make_float2(a.x+b.x, a.y+b.y);
            y[h+j+2] = (j == 0) ? d : make_float2(sg*d.y, -sg*d.x);
        }
    #pragma unroll
    for (int h = 0; h < 16; h += 2) {
        float2 a = y[h], b = y[h+1];
        y[h] = make_float2(a.x+b.x, a.y+b.y);
        y[h+1] = make_float2(a.x-b.x, a.y-b.y);
    }
}

// ---- full 16-point DIF DFT. Output: Y[k] = y[rev4[k]]. ----
template<bool INV>
__device__ __forceinline__ void fft16(float2* y) {
    const float sg = INV ? -1.f : 1.f;
    const float WR[8] = {1.f, C16_1, C16_2, C16_3, 0.f, -C16_3, -C16_2, -C16_1};
    const float WI[8] = {0.f, -C16_3, -C16_2, -C16_1, -1.f, -C16_1, -C16_2, -C16_3};
    #pragma unroll
    for (int j = 0; j < 8; ++j) {
        float2 a = y[j], b = y[j+8];
        float2 d = make_float2(a.x-b.x, a.y-b.y);
        y[j] = make_float2(a.x+b.x, a.y+b.y);
        y[j+8] = cmulw(d, WR[j], sg*WI[j]);
    }
    fft16_tail<INV>(y);
}

// ---- 8-point DIF DFT. Output: Y[k] = y[rev3[k]]. ----
template<bool INV>
__device__ __forceinline__ void fft8(float2* y) {
    const float sg = INV ? -1.f : 1.f;
    const float WR[4] = {1.f, C16_2, 0.f, -C16_2};
    const float WI[4] = {0.f, -C16_2, -1.f, -C16_2};
    #pragma unroll
    for (int j = 0; j < 4; ++j) {
        float2 a = y[j], b = y[j+4];
        float2 d = make_float2(a.x-b.x, a.y-b.y);
        y[j] = make_float2(a.x+b.x, a.y+b.y);
        y[j+4] = cmulw(d, WR[j], sg*WI[j]);
    }
    #pragma unroll
    for (int h = 0; h < 8; h += 4)
        #pragma unroll
        for (int j = 0; j < 2; ++j) {
            float2 a = y[h+j], b = y[h+j+2];
            float2 d = make_float2(a.x-b.x, a.y-b.y);
            y[h+j] = make_float2(a.x+b.x, a.y+b.y);
            y[h+j+2] = (j == 0) ? d : make_float2(sg*d.y, -sg*d.x);
        }
    #pragma unroll
    for (int h = 0; h < 8; h += 2) {
        float2 a = y[h], b = y[h+1];
        y[h] = make_float2(a.x+b.x, a.y+b.y);
        y[h+1] = make_float2(a.x-b.x, a.y-b.y);
    }
}

// Radix-16 pass on swizzled LDS. INV=false: DIF forward (natural->DR).
// INV=true: DIT inverse (DR->natural).
template<bool INV>
__device__ __forceinline__ void pass16(float2* s, int base, int str, float ang1) {
    const int rev4[16] = {0,8,4,12,2,10,6,14,1,9,5,13,3,11,7,15};
    float2 y[16];
    float sn, cs;
    __sincosf(ang1, &sn, &cs);
    float2 wb = make_float2(cs, sn);
    if (!INV) {
        #pragma unroll
        for (int j = 0; j < 16; ++j) y[j] = s[SW(base + j*str)];
        fft16<false>(y);
        float2 w = make_float2(1.f, 0.f);
        s[SW(base)] = y[0];
        #pragma unroll
        for (int k = 1; k < 16; ++k) {
            w = cmul(w, wb);
            s[SW(base + k*str)] = cmul(y[rev4[k]], w);
        }
    } else {
        float2 w = make_float2(1.f, 0.f);
        y[0] = s[SW(base)];
        #pragma unroll
        for (int k = 1; k < 16; ++k) {
            w = cmul(w, wb);
            y[k] = cmul(s[SW(base + k*str)], w);
        }
        fft16<true>(y);
        #pragma unroll
        for (int j = 0; j < 16; ++j) s[SW(base + j*str)] = y[rev4[j]];
    }
}

// Forward radix-16 pass with implicit-zero top half (j>=8 inputs are zero):
// skips 8 LDS reads; stage-1 butterfly with b=0 is a twiddled copy.
__device__ __forceinline__ void pass16_z(float2* s, int base, int str, float ang1) {
    const int rev4[16] = {0,8,4,12,2,10,6,14,1,9,5,13,3,11,7,15};
    const float WR[8] = {1.f, C16_1, C16_2, C16_3, 0.f, -C16_3, -C16_2, -C16_1};
    const float WI[8] = {0.f, -C16_3, -C16_2, -C16_1, -1.f, -C16_1, -C16_2, -C16_3};
    float2 y[16];
    float sn, cs;
    __sincosf(ang1, &sn, &cs);
    float2 wb = make_float2(cs, sn);
    #pragma unroll
    for (int j = 0; j < 8; ++j) y[j] = s[SW(base + j*str)];
    #pragma unroll
    for (int j = 0; j < 8; ++j) y[j+8] = cmulw(y[j], WR[j], WI[j]);
    fft16_tail<false>(y);
    float2 w = make_float2(1.f, 0.f);
    s[SW(base)] = y[0];
    #pragma unroll
    for (int k = 1; k < 16; ++k) {
        w = cmul(w, wb);
        s[SW(base + k*str)] = cmul(y[rev4[k]], w);
    }
}

// Final inverse radix-16 pass: only j<8 outputs (t<2048) are needed.
__device__ __forceinline__ void pass16_li(float2* s, int base, int str, float ang1) {
    const int rev4[16] = {0,8,4,12,2,10,6,14,1,9,5,13,3,11,7,15};
    float2 y[16];
    float sn, cs;
    __sincosf(ang1, &sn, &cs);
    float2 wb = make_float2(cs, sn);
    float2 w = make_float2(1.f, 0.f);
    y[0] = s[SW(base)];
    #pragma unroll
    for (int k = 1; k < 16; ++k) {
        w = cmul(w, wb);
        y[k] = cmul(s[SW(base + k*str)], w);
    }
    fft16<true>(y);
    #pragma unroll
    for (int j = 0; j < 8; ++j) s[SW(base + j*str)] = y[rev4[j]];
}

template<bool INV>
__device__ __forceinline__ void pass8(float2* s, int base, int str, float ang1) {
    const int rev3[8] = {0,4,2,6,1,5,3,7};
    float2 y[8];
    float sn, cs;
    __sincosf(ang1, &sn, &cs);
    float2 wb = make_float2(cs, sn);
    if (!INV) {
        #pragma unroll
        for (int j = 0; j < 8; ++j) y[j] = s[SW(base + j*str)];
        fft8<false>(y);
        float2 w = make_float2(1.f, 0.f);
        s[SW(base)] = y[0];
        #pragma unroll
        for (int k = 1; k < 8; ++k) {
            w = cmul(w, wb);
            s[SW(base + k*str)] = cmul(y[rev3[k]], w);
        }
    } else {
        float2 w = make_float2(1.f, 0.f);
        y[0] = s[SW(base)];
        #pragma unroll
        for (int k = 1; k < 8; ++k) {
            w = cmul(w, wb);
            y[k] = cmul(s[SW(base + k*str)], w);
        }
        fft8<true>(y);
        #pragma unroll
        for (int j = 0; j < 8; ++j) s[SW(base + j*str)] = y[rev3[j]];
    }
}

__device__ __forceinline__ float2 finalize_ar(const float* s, float tg) {
    float denx = 1.0f + s[6], deny = s[7];
    float dinv = 1.0f / (denx*denx + deny*deny);
    float numx = s[2]*s[4] - s[3]*s[5];
    float numy = s[2]*s[5] + s[3]*s[4];
    float qx = (numx*denx + numy*deny) * dinv;
    float qy = (numy*denx - numx*deny) * dinv;
    float kx = s[0] - qx, ky = s[1] - qy;
    return make_float2(kx - tg*ky, ky + tg*kx);   // (1 + i*tg) * k
}

// Cauchy evaluation: 4 blocks per head, 1 l-pair per thread.
// Writes A[0..1024] (Hermitian half) natural-order, coalesced.
__global__ __launch_bounds__(NTH) void k_cauchy(
    const float* __restrict__ Lre, const float* __restrict__ Lim,
    const float* __restrict__ Pm, const float* __restrict__ Bm,
    const float* __restrict__ Cm, const float* __restrict__ logstep,
    float2* __restrict__ Ag)
{
    __shared__ float4 cA[NS];   // dre, dre^2, lam_im, |P|^2
    __shared__ float4 cB[NS];   // conj(C)B, conj(C)P
    __shared__ float2 cC[NS];   // conj(P)B
    const int h = blockIdx.x >> 2;
    const int q = blockIdx.x & 3;
    const int tid = threadIdx.x;
    if (tid < NS) {
        int i = h * NS + tid;
        float Lx = fminf(Lre[i], -1e-4f), Ly = Lim[i];
        float Px = Pm[2*i], Py = Pm[2*i+1];
        float Bx = Bm[2*i], By = Bm[2*i+1];
        float Cx = Cm[2*i], Cy = Cm[2*i+1];
        float dre = -Lx;
        cA[tid] = make_float4(dre, dre*dre, Ly, Px*Px + Py*Py);
        cB[tid] = make_float4(Cx*Bx + Cy*By, Cx*By - Cy*Bx,
                              Cx*Px + Cy*Py, Cx*Py - Cy*Px);
        cC[tid] = make_float2(Px*Bx + Py*By, Px*By - Py*Bx);
    }
    __syncthreads();
    const float step = expf(logstep[h]);
    const float a2s = 2.0f / step;
    const int l = q * NTH + tid;                 // l in [0, 1024)
    float r = (float)l * (1.0f / (float)LSEQ);
    float tg = sinpif(r) / cospif(r);            // tan(pi*l/L); tg(L-l) = -tg
    float g1 = a2s * tg;
    float sa[8] = {0,0,0,0,0,0,0,0};
    float sb[8] = {0,0,0,0,0,0,0,0};
    #pragma unroll 4
    for (int n = 0; n < NS; ++n) {
        float4 ca = cA[n];
        float4 cb = cB[n];
        float2 cc = cC[n];
        float di1 = g1 - ca.z;
        float di2 = -g1 - ca.z;
        float iv1 = 1.0f / fmaf(di1, di1, ca.y);
        float iv2 = 1.0f / fmaf(di2, di2, ca.y);
        float rx1 = ca.x*iv1, ry1 = di1*iv1;     // rec = rx - i*ry
        float rx2 = ca.x*iv2, ry2 = di2*iv2;
        sa[0] += cb.x*rx1 + cb.y*ry1;  sa[1] += cb.y*rx1 - cb.x*ry1;
        sa[2] += cb.z*rx1 + cb.w*ry1;  sa[3] += cb.w*rx1 - cb.z*ry1;
        sa[4] += cc.x*rx1 + cc.y*ry1;  sa[5] += cc.y*rx1 - cc.x*ry1;
        sa[6] += ca.w*rx1;             sa[7] -= ca.w*ry1;
        sb[0] += cb.x*rx2 + cb.y*ry2;  sb[1] += cb.y*rx2 - cb.x*ry2;
        sb[2] += cb.z*rx2 + cb.w*ry2;  sb[3] += cb.w*rx2 - cb.z*ry2;
        sb[4] += cc.x*rx2 + cc.y*ry2;  sb[5] += cc.y*rx2 - cc.x*ry2;
        sb[6] += ca.w*rx2;             sb[7] -= ca.w*ry2;
    }
    float2 ar1 = finalize_ar(sa, tg);
    float2 ar2 = finalize_ar(sb, -tg);
    // A[l] = (at[l] + conj(at[2048-l]))/2
    float2 A = make_float2(0.5f*(ar1.x + ar2.x), 0.5f*(ar1.y - ar2.y));
    Ag[(size_t)h * ASTR + l] = A;
    if (q == 0 && tid == 0) {
        // l = 1024: tan -> inf limit, c_scale*k -> (step/2)*sum(conj(C)B)
        float sx = 0.f;
        for (int n = 0; n < NS; ++n) sx += cB[n].x;
        Ag[(size_t)h * ASTR + 1024] = make_float2(0.5f * step * sx, 0.f);
    }
}

// Kernel spectrum: 2 heads per block (128 threads each). Reads A half,
// mirrors conjugates, IDIT-2048 -> modulate -> DIF-2048, writes all 4096
// Kf bins (dr12-permuted layout) coalesced. +D and 1/4096 folded in.
__global__ __launch_bounds__(NTH, 2) void k_kspec(
    const float2* __restrict__ Ag, const float* __restrict__ Dp,
    float2* __restrict__ KfP)
{
    __shared__ float2 sWs[2][LSEQ];
    __shared__ float2 sAs[2][LSEQ];
    const int half = threadIdx.x >> 7;
    const int t7 = threadIdx.x & 127;
    const int hh = blockIdx.x * 2 + half;
    float2* sW = sWs[half];
    float2* sA = sAs[half];
    const float2* Ah = Ag + (size_t)hh * ASTR;
    for (int l = t7; l <= LSEQ/2; l += 128) {
        float2 A = Ah[l];
        sA[l] = A;
        sW[SW(DR11(l))] = A;
        if (l > 0 && l < LSEQ/2) {
            int l2 = LSEQ - l;
            float2 Ac = make_float2(A.x, -A.y);
            sA[l2] = Ac;
            sW[SW(DR11(l2))] = Ac;
        }
    }
    __syncthreads();
    // inverse DIT-2048 (DR -> natural time)
    pass8<true>(sW, t7 << 3, 1, 0.f);
    pass8<true>(sW, (t7 + 128) << 3, 1, 0.f);
    __syncthreads();
    pass16<true>(sW, ((t7 >> 3) << 7) | (t7 & 7), 8,
                 TWO_PI * (float)(t7 & 7) / 128.f);
    __syncthreads();
    pass16<true>(sW, t7, 128, TWO_PI * (float)t7 / 2048.f);
    __syncthreads();
    // modulate: K[t]/2048 * e^{-2pi i t/4096}
    for (int t = t7; t < LSEQ; t += 128) {
        float kv = sW[SW(t)].x * (1.0f / (float)LSEQ);
        float sn, cs;
        __sincosf(-TWO_PI * (float)t / (float)NF, &sn, &cs);
        sW[SW(t)] = make_float2(kv * cs, kv * sn);
    }
    __syncthreads();
    // forward DIF-2048 (natural -> DR spectrum)
    pass16<false>(sW, t7, 128, -TWO_PI * (float)t7 / 2048.f);
    __syncthreads();
    pass16<false>(sW, ((t7 >> 3) << 7) | (t7 & 7), 8,
                  -TWO_PI * (float)(t7 & 7) / 128.f);
    __syncthreads();
    pass8<false>(sW, t7 << 3, 1, 0.f);
    pass8<false>(sW, (t7 + 128) << 3, 1, 0.f);
    __syncthreads();
    const float dD = Dp[hh];
    const float s4 = 1.0f / (float)NF;
    float2* Kh = KfP + (size_t)hh * NF;
    for (int p = t7; p < NF; p += 128) {
        int k = ((p & 15) << 8) | (p & 240) | (p >> 8);   // bin at position p
        float2 v;
        if (k & 1) {
            int m = k >> 1;
            v = sW[SW(DR11(m))];
        } else {
            v = sA[k >> 1];
        }
        Kh[p] = make_float2((v.x + dD) * s4, v.y * s4);
    }
}

// FFT convolution per (b, head-pair): pack 2 real rows as complex, forward
// DIF-4096 (spectrum stays dr12-permuted), Hermitian split+multiply with
// permuted Kf, inverse DIT-4096, store. +D*u and 1/4096 folded into Kf.
__global__ __launch_bounds__(NTH, 5) void k_conv(
    const float2* __restrict__ u2, const float2* __restrict__ Kf,
    float2* __restrict__ out2)
{
    __shared__ float2 s[NF];
    const int idx = blockIdx.x;
    const int x = idx & 7, m = idx >> 3;
    const int b = m >> 5;
    const int hp = x * 32 + (m & 31);   // XCD swizzle: adjacent hp same XCD
    const int tid = threadIdx.x;
    const float2* ub = u2 + (size_t)b * LSEQ * NPAIR + hp;
    for (int t = tid; t < LSEQ; t += NTH) s[SW(t)] = ub[(size_t)t * NPAIR];
    __syncthreads();
    // forward DIF 4096 = 16*16*16 (pass 1 exploits zero top half)
    pass16_z(s, tid, 256, -TWO_PI * (float)tid / 4096.f);
    __syncthreads();
    pass16<false>(s, ((tid >> 4) << 8) | (tid & 15), 16,
                  -TWO_PI * (float)(tid & 15) / 256.f);
    __syncthreads();
    pass16<false>(s, tid << 4, 1, 0.f);
    __syncthreads();
    // pointwise in permuted domain
    const float2* K0 = Kf + (size_t)(2 * hp) * NF;
    const float2* K1 = K0 + NF;
    for (int p = tid; p < NF; p += NTH) {
        int k  = ((p & 15) << 8) | (p & 240) | (p >> 8);       // bin at pos p
        int kc = (NF - k) & (NF - 1);
        int pp = ((kc & 15) << 8) | (kc & 240) | (kc >> 8);    // conj bin pos
        if (p > pp) continue;
        if (p == pp) {   // self-conjugate bins (k = 0, 2048)
            float2 X = s[SW(p)];
            float2 g0 = K0[p], g1 = K1[p];
            s[SW(p)] = make_float2(X.x*g0.x - X.y*g1.y, X.x*g0.y + X.y*g1.x);
        } else {
            float2 Xa = s[SW(p)], Xb = s[SW(pp)];
            float2 U0 = make_float2(0.5f*(Xa.x + Xb.x), 0.5f*(Xa.y - Xb.y));
            float2 df = make_float2(Xa.x - Xb.x, Xa.y + Xb.y);
            float2 U1 = make_float2(0.5f*df.y, -0.5f*df.x);
            float2 A0 = K0[p], A1 = K1[p], B0 = K0[pp], B1 = K1[pp];
            float2 y0 = cmul(U0, A0), y1 = cmul(U1, A1);
            s[SW(p)] = make_float2(y0.x - y1.y, y0.y + y1.x);
            float2 U0c = make_float2(U0.x, -U0.y);
            float2 U1c = make_float2(U1.x, -U1.y);
            float2 z0 = cmul(U0c, B0), z1 = cmul(U1c, B1);
            s[SW(pp)] = make_float2(z0.x - z1.y, z0.y + z1.x);
        }
    }
    __syncthreads();
    // inverse DIT 4096 (last pass writes only t<2048)
    pass16<true>(s, tid << 4, 1, 0.f);
    __syncthreads();
    pass16<true>(s, ((tid >> 4) << 8) | (tid & 15), 16,
                 TWO_PI * (float)(tid & 15) / 256.f);
    __syncthreads();
    pass16_li(s, tid, 256, TWO_PI * (float)tid / 4096.f);
    __syncthreads();
    float2* ob = out2 + (size_t)b * LSEQ * NPAIR + hp;
    for (int t = tid; t < LSEQ; t += NTH) ob[(size_t)t * NPAIR] = s[SW(t)];
}

extern "C" void kernel_launch(void* const* d_in, const int* in_sizes, int n_in,
                              void* d_out, int out_size, void* d_ws, size_t ws_size,
                              hipStream_t stream) {
    const float* u   = (const float*)d_in[0];
    const float* Lre = (const float*)d_in[1];
    const float* Lim = (const float*)d_in[2];
    const float* P   = (const float*)d_in[3];
    const float* B   = (const float*)d_in[4];
    const float* C   = (const float*)d_in[5];
    const float* D   = (const float*)d_in[6];
    const float* ls  = (const float*)d_in[7];

    float2* KfP = (float2*)d_ws;          // 16 MB: permuted kernel spectrum
    float2* Ag  = (float2*)d_out;         // 4.3 MB scratch, later overwritten

    k_cauchy<<<NH * 4, NTH, 0, stream>>>(Lre, Lim, P, B, C, ls, Ag);
    k_kspec <<<NH / 2, NTH, 0, stream>>>(Ag, D, KfP);
    k_conv  <<<NB * NPAIR, NTH, 0, stream>>>((const float2*)u, KfP,
                                             (float2*)d_out);
}

// Round 6
// 269.569 us; speedup vs baseline: 1.0481x; 1.0481x over previous
//
#include <hip/hip_runtime.h>
#include <math.h>

#define NTH 256
#define LSEQ 2048
#define NF 4096
#define NH 512
#define NS 64
#define NB 8
#define NPAIR 256
#define ASTR 1040
#define TWO_PI 6.2831853071795864769f
// XOR swizzle: bijective, modifies only bits 0-3; spreads every FFT pass's
// lane pattern evenly over banks.
#define SW(i) ((i) ^ (((i) >> 4) & 15) ^ (((i) >> 8) & 15))
#define DR11(l) ((((l) & 15) << 7) | ((((l) >> 4) & 15) << 3) | ((l) >> 8))

#define C16_1 0.9238795325112867f
#define C16_2 0.7071067811865476f
#define C16_3 0.3826834323650898f

__device__ __forceinline__ float2 cmul(float2 a, float2 b) {
    return make_float2(a.x*b.x - a.y*b.y, a.x*b.y + a.y*b.x);
}
__device__ __forceinline__ float2 cmulw(float2 a, float wr, float wi) {
    return make_float2(a.x*wr - a.y*wi, a.x*wi + a.y*wr);
}

// ---- stages 2..4 of the 16-point DIF DFT (shared tail) ----
template<bool INV>
__device__ __forceinline__ void fft16_tail(float2* y) {
    const float sg = INV ? -1.f : 1.f;
    const float WR[8] = {1.f, C16_1, C16_2, C16_3, 0.f, -C16_3, -C16_2, -C16_1};
    const float WI[8] = {0.f, -C16_3, -C16_2, -C16_1, -1.f, -C16_1, -C16_2, -C16_3};
    #pragma unroll
    for (int h = 0; h < 16; h += 8)
        #pragma unroll
        for (int j = 0; j < 4; ++j) {
            float2 a = y[h+j], b = y[h+j+4];
            float2 d = make_float2(a.x-b.x, a.y-b.y);
            y[h+j] = make_float2(a.x+b.x, a.y+b.y);
            y[h+j+4] = cmulw(d, WR[2*j], sg*WI[2*j]);
        }
    #pragma unroll
    for (int h = 0; h < 16; h += 4)
        #pragma unroll
        for (int j = 0; j < 2; ++j) {
            float2 a = y[h+j], b = y[h+j+2];
            float2 d = make_float2(a.x-b.x, a.y-b.y);
            y[h+j] = make_float2(a.x+b.x, a.y+b.y);
            y[h+j+2] = (j == 0) ? d : make_float2(sg*d.y, -sg*d.x);
        }
    #pragma unroll
    for (int h = 0; h < 16; h += 2) {
        float2 a = y[h], b = y[h+1];
        y[h] = make_float2(a.x+b.x, a.y+b.y);
        y[h+1] = make_float2(a.x-b.x, a.y-b.y);
    }
}

// ---- full 16-point DIF DFT. Output: Y[k] = y[rev4[k]]. ----
template<bool INV>
__device__ __forceinline__ void fft16(float2* y) {
    const float sg = INV ? -1.f : 1.f;
    const float WR[8] = {1.f, C16_1, C16_2, C16_3, 0.f, -C16_3, -C16_2, -C16_1};
    const float WI[8] = {0.f, -C16_3, -C16_2, -C16_1, -1.f, -C16_1, -C16_2, -C16_3};
    #pragma unroll
    for (int j = 0; j < 8; ++j) {
        float2 a = y[j], b = y[j+8];
        float2 d = make_float2(a.x-b.x, a.y-b.y);
        y[j] = make_float2(a.x+b.x, a.y+b.y);
        y[j+8] = cmulw(d, WR[j], sg*WI[j]);
    }
    fft16_tail<INV>(y);
}

// ---- 8-point DIF DFT. Output: Y[k] = y[rev3[k]]. ----
template<bool INV>
__device__ __forceinline__ void fft8(float2* y) {
    const float sg = INV ? -1.f : 1.f;
    const float WR[4] = {1.f, C16_2, 0.f, -C16_2};
    const float WI[4] = {0.f, -C16_2, -1.f, -C16_2};
    #pragma unroll
    for (int j = 0; j < 4; ++j) {
        float2 a = y[j], b = y[j+4];
        float2 d = make_float2(a.x-b.x, a.y-b.y);
        y[j] = make_float2(a.x+b.x, a.y+b.y);
        y[j+4] = cmulw(d, WR[j], sg*WI[j]);
    }
    #pragma unroll
    for (int h = 0; h < 8; h += 4)
        #pragma unroll
        for (int j = 0; j < 2; ++j) {
            float2 a = y[h+j], b = y[h+j+2];
            float2 d = make_float2(a.x-b.x, a.y-b.y);
            y[h+j] = make_float2(a.x+b.x, a.y+b.y);
            y[h+j+2] = (j == 0) ? d : make_float2(sg*d.y, -sg*d.x);
        }
    #pragma unroll
    for (int h = 0; h < 8; h += 2) {
        float2 a = y[h], b = y[h+1];
        y[h] = make_float2(a.x+b.x, a.y+b.y);
        y[h+1] = make_float2(a.x-b.x, a.y-b.y);
    }
}

// Radix-16 pass on swizzled LDS. INV=false: DIF forward (natural->DR).
// INV=true: DIT inverse (DR->natural).
template<bool INV>
__device__ __forceinline__ void pass16(float2* s, int base, int str, float ang1) {
    const int rev4[16] = {0,8,4,12,2,10,6,14,1,9,5,13,3,11,7,15};
    float2 y[16];
    float sn, cs;
    __sincosf(ang1, &sn, &cs);
    float2 wb = make_float2(cs, sn);
    if (!INV) {
        #pragma unroll
        for (int j = 0; j < 16; ++j) y[j] = s[SW(base + j*str)];
        fft16<false>(y);
        float2 w = make_float2(1.f, 0.f);
        s[SW(base)] = y[0];
        #pragma unroll
        for (int k = 1; k < 16; ++k) {
            w = cmul(w, wb);
            s[SW(base + k*str)] = cmul(y[rev4[k]], w);
        }
    } else {
        float2 w = make_float2(1.f, 0.f);
        y[0] = s[SW(base)];
        #pragma unroll
        for (int k = 1; k < 16; ++k) {
            w = cmul(w, wb);
            y[k] = cmul(s[SW(base + k*str)], w);
        }
        fft16<true>(y);
        #pragma unroll
        for (int j = 0; j < 16; ++j) s[SW(base + j*str)] = y[rev4[j]];
    }
}

// Forward radix-16 pass with implicit-zero top half (j>=8 inputs are zero).
__device__ __forceinline__ void pass16_z(float2* s, int base, int str, float ang1) {
    const int rev4[16] = {0,8,4,12,2,10,6,14,1,9,5,13,3,11,7,15};
    const float WR[8] = {1.f, C16_1, C16_2, C16_3, 0.f, -C16_3, -C16_2, -C16_1};
    const float WI[8] = {0.f, -C16_3, -C16_2, -C16_1, -1.f, -C16_1, -C16_2, -C16_3};
    float2 y[16];
    float sn, cs;
    __sincosf(ang1, &sn, &cs);
    float2 wb = make_float2(cs, sn);
    #pragma unroll
    for (int j = 0; j < 8; ++j) y[j] = s[SW(base + j*str)];
    #pragma unroll
    for (int j = 0; j < 8; ++j) y[j+8] = cmulw(y[j], WR[j], WI[j]);
    fft16_tail<false>(y);
    float2 w = make_float2(1.f, 0.f);
    s[SW(base)] = y[0];
    #pragma unroll
    for (int k = 1; k < 16; ++k) {
        w = cmul(w, wb);
        s[SW(base + k*str)] = cmul(y[rev4[k]], w);
    }
}

// Final inverse radix-16 pass: only j<8 outputs (t<2048) are needed.
__device__ __forceinline__ void pass16_li(float2* s, int base, int str, float ang1) {
    const int rev4[16] = {0,8,4,12,2,10,6,14,1,9,5,13,3,11,7,15};
    float2 y[16];
    float sn, cs;
    __sincosf(ang1, &sn, &cs);
    float2 wb = make_float2(cs, sn);
    float2 w = make_float2(1.f, 0.f);
    y[0] = s[SW(base)];
    #pragma unroll
    for (int k = 1; k < 16; ++k) {
        w = cmul(w, wb);
        y[k] = cmul(s[SW(base + k*str)], w);
    }
    fft16<true>(y);
    #pragma unroll
    for (int j = 0; j < 8; ++j) s[SW(base + j*str)] = y[rev4[j]];
}

template<bool INV>
__device__ __forceinline__ void pass8(float2* s, int base, int str, float ang1) {
    const int rev3[8] = {0,4,2,6,1,5,3,7};
    float2 y[8];
    float sn, cs;
    __sincosf(ang1, &sn, &cs);
    float2 wb = make_float2(cs, sn);
    if (!INV) {
        #pragma unroll
        for (int j = 0; j < 8; ++j) y[j] = s[SW(base + j*str)];
        fft8<false>(y);
        float2 w = make_float2(1.f, 0.f);
        s[SW(base)] = y[0];
        #pragma unroll
        for (int k = 1; k < 8; ++k) {
            w = cmul(w, wb);
            s[SW(base + k*str)] = cmul(y[rev3[k]], w);
        }
    } else {
        float2 w = make_float2(1.f, 0.f);
        y[0] = s[SW(base)];
        #pragma unroll
        for (int k = 1; k < 8; ++k) {
            w = cmul(w, wb);
            y[k] = cmul(s[SW(base + k*str)], w);
        }
        fft8<true>(y);
        #pragma unroll
        for (int j = 0; j < 8; ++j) s[SW(base + j*str)] = y[rev3[j]];
    }
}

__device__ __forceinline__ float2 finalize_ar(const float* s, float tg) {
    float denx = 1.0f + s[6], deny = s[7];
    float dinv = 1.0f / (denx*denx + deny*deny);
    float numx = s[2]*s[4] - s[3]*s[5];
    float numy = s[2]*s[5] + s[3]*s[4];
    float qx = (numx*denx + numy*deny) * dinv;
    float qy = (numy*denx - numx*deny) * dinv;
    float kx = s[0] - qx, ky = s[1] - qy;
    return make_float2(kx - tg*ky, ky + tg*kx);   // (1 + i*tg) * k
}

// Transpose u [b][t][hp]f2 -> W [hp][b][t]f2 via 64x64 LDS tiles.
__global__ __launch_bounds__(NTH) void k_tu(
    const float2* __restrict__ u2, float2* __restrict__ W)
{
    __shared__ float2 tile[64][65];
    const int t0 = blockIdx.x * 64, hp0 = blockIdx.y * 64, b = blockIdx.z;
    const int tx = threadIdx.x & 63, ty = threadIdx.x >> 6;
    #pragma unroll
    for (int r = 0; r < 64; r += 4)
        tile[r + ty][tx] = u2[((size_t)b * LSEQ + t0 + r + ty) * NPAIR + hp0 + tx];
    __syncthreads();
    #pragma unroll
    for (int r = 0; r < 64; r += 4)
        W[(((size_t)(hp0 + r + ty) * NB + b) << 11) + t0 + tx] = tile[tx][r + ty];
}

// Transpose W [hp][b][t]f2 -> out [b][t][hp]f2.
__global__ __launch_bounds__(NTH) void k_ty(
    const float2* __restrict__ W, float2* __restrict__ out2)
{
    __shared__ float2 tile[64][65];
    const int t0 = blockIdx.x * 64, hp0 = blockIdx.y * 64, b = blockIdx.z;
    const int tx = threadIdx.x & 63, ty = threadIdx.x >> 6;
    #pragma unroll
    for (int r = 0; r < 64; r += 4)   // tile[hp_local][t_local]
        tile[r + ty][tx] = W[(((size_t)(hp0 + r + ty) * NB + b) << 11) + t0 + tx];
    __syncthreads();
    #pragma unroll
    for (int r = 0; r < 64; r += 4)
        out2[((size_t)b * LSEQ + t0 + r + ty) * NPAIR + hp0 + tx] = tile[tx][r + ty];
}

// Cauchy evaluation: 4 blocks per head, 1 l-pair per thread.
// Writes A[0..1024] natural-order (for k_kspec) AND the even Kf bins
// directly (permuted positions).
__global__ __launch_bounds__(NTH) void k_cauchy(
    const float* __restrict__ Lre, const float* __restrict__ Lim,
    const float* __restrict__ Pm, const float* __restrict__ Bm,
    const float* __restrict__ Cm, const float* __restrict__ Dp,
    const float* __restrict__ logstep,
    float2* __restrict__ Ag, float2* __restrict__ KfP)
{
    __shared__ float4 cA[NS];   // dre, dre^2, lam_im, |P|^2
    __shared__ float4 cB[NS];   // conj(C)B, conj(C)P
    __shared__ float2 cC[NS];   // conj(P)B
    const int h = blockIdx.x >> 2;
    const int q = blockIdx.x & 3;
    const int tid = threadIdx.x;
    if (tid < NS) {
        int i = h * NS + tid;
        float Lx = fminf(Lre[i], -1e-4f), Ly = Lim[i];
        float Px = Pm[2*i], Py = Pm[2*i+1];
        float Bx = Bm[2*i], By = Bm[2*i+1];
        float Cx = Cm[2*i], Cy = Cm[2*i+1];
        float dre = -Lx;
        cA[tid] = make_float4(dre, dre*dre, Ly, Px*Px + Py*Py);
        cB[tid] = make_float4(Cx*Bx + Cy*By, Cx*By - Cy*Bx,
                              Cx*Px + Cy*Py, Cx*Py - Cy*Px);
        cC[tid] = make_float2(Px*Bx + Py*By, Px*By - Py*Bx);
    }
    __syncthreads();
    const float step = expf(logstep[h]);
    const float a2s = 2.0f / step;
    const float dD = Dp[h];
    const float s4 = 1.0f / (float)NF;
    float2* Kh = KfP + (size_t)h * NF;
    const int l = q * NTH + tid;                 // l in [0, 1024)
    float r = (float)l * (1.0f / (float)LSEQ);
    float tg = sinpif(r) / cospif(r);            // tan(pi*l/L); tg(L-l) = -tg
    float g1 = a2s * tg;
    float sa[8] = {0,0,0,0,0,0,0,0};
    float sb[8] = {0,0,0,0,0,0,0,0};
    #pragma unroll 4
    for (int n = 0; n < NS; ++n) {
        float4 ca = cA[n];
        float4 cb = cB[n];
        float2 cc = cC[n];
        float di1 = g1 - ca.z;
        float di2 = -g1 - ca.z;
        float iv1 = 1.0f / fmaf(di1, di1, ca.y);
        float iv2 = 1.0f / fmaf(di2, di2, ca.y);
        float rx1 = ca.x*iv1, ry1 = di1*iv1;     // rec = rx - i*ry
        float rx2 = ca.x*iv2, ry2 = di2*iv2;
        sa[0] += cb.x*rx1 + cb.y*ry1;  sa[1] += cb.y*rx1 - cb.x*ry1;
        sa[2] += cb.z*rx1 + cb.w*ry1;  sa[3] += cb.w*rx1 - cb.z*ry1;
        sa[4] += cc.x*rx1 + cc.y*ry1;  sa[5] += cc.y*rx1 - cc.x*ry1;
        sa[6] += ca.w*rx1;             sa[7] -= ca.w*ry1;
        sb[0] += cb.x*rx2 + cb.y*ry2;  sb[1] += cb.y*rx2 - cb.x*ry2;
        sb[2] += cb.z*rx2 + cb.w*ry2;  sb[3] += cb.w*rx2 - cb.z*ry2;
        sb[4] += cc.x*rx2 + cc.y*ry2;  sb[5] += cc.y*rx2 - cc.x*ry2;
        sb[6] += ca.w*rx2;             sb[7] -= ca.w*ry2;
    }
    float2 ar1 = finalize_ar(sa, tg);
    float2 ar2 = finalize_ar(sb, -tg);
    // A[l] = (at[l] + conj(at[2048-l]))/2
    float2 A = make_float2(0.5f*(ar1.x + ar2.x), 0.5f*(ar1.y - ar2.y));
    Ag[(size_t)h * ASTR + l] = A;
    int k1 = 2 * l;
    Kh[((k1&15)<<8) | (k1&240) | (k1>>8)] = make_float2((A.x + dD)*s4, A.y*s4);
    if (l > 0) {
        int k2 = NF - k1;
        Kh[((k2&15)<<8) | (k2&240) | (k2>>8)] =
            make_float2((A.x + dD)*s4, -A.y*s4);
    }
    if (q == 0 && tid == 0) {
        // l = 1024: tan -> inf limit, c_scale*k -> (step/2)*sum(conj(C)B)
        float sx = 0.f;
        for (int n = 0; n < NS; ++n) sx += cB[n].x;
        float2 Am = make_float2(0.5f * step * sx, 0.f);
        Ag[(size_t)h * ASTR + 1024] = Am;
        Kh[8] = make_float2((Am.x + dD) * s4, 0.f);   // bin 2048 lives at pos 8
    }
}

// Odd Kf bins: one head per block (512 blocks, 16 KB LDS).
// IDIT-2048(A) -> K -> modulate e^{-2pi i t/4096} -> DIF-2048 -> odd bins.
__global__ __launch_bounds__(NTH) void k_kspec(
    const float2* __restrict__ Ag, const float* __restrict__ Dp,
    float2* __restrict__ KfP)
{
    __shared__ float2 sW[LSEQ];
    const int h = blockIdx.x;
    const int tid = threadIdx.x;
    const float2* Ah = Ag + (size_t)h * ASTR;
    for (int l = tid; l <= LSEQ/2; l += NTH) {
        float2 A = Ah[l];
        sW[SW(DR11(l))] = A;
        if (l > 0 && l < LSEQ/2)
            sW[SW(DR11(LSEQ - l))] = make_float2(A.x, -A.y);
    }
    __syncthreads();
    // inverse DIT-2048 (DR -> natural time)
    pass8<true>(sW, tid << 3, 1, 0.f);
    __syncthreads();
    if (tid < 128) pass16<true>(sW, ((tid >> 3) << 7) | (tid & 7), 8,
                                TWO_PI * (float)(tid & 7) / 128.f);
    __syncthreads();
    if (tid < 128) pass16<true>(sW, tid, 128, TWO_PI * (float)tid / 2048.f);
    __syncthreads();
    // modulate: K[t]/2048 * e^{-2pi i t/4096}
    for (int t = tid; t < LSEQ; t += NTH) {
        float kv = sW[SW(t)].x * (1.0f / (float)LSEQ);
        float sn, cs;
        __sincosf(-TWO_PI * (float)t / (float)NF, &sn, &cs);
        sW[SW(t)] = make_float2(kv * cs, kv * sn);
    }
    __syncthreads();
    // forward DIF-2048 (natural -> DR spectrum)
    if (tid < 128) pass16<false>(sW, tid, 128, -TWO_PI * (float)tid / 2048.f);
    __syncthreads();
    if (tid < 128) pass16<false>(sW, ((tid >> 3) << 7) | (tid & 7), 8,
                                 -TWO_PI * (float)(tid & 7) / 128.f);
    __syncthreads();
    pass8<false>(sW, tid << 3, 1, 0.f);
    __syncthreads();
    const float dD = Dp[h];
    const float s4 = 1.0f / (float)NF;
    float2* Kh = KfP + (size_t)h * NF;
    #pragma unroll
    for (int g = 0; g < 8; ++g) {      // positions with (p>>8) odd <=> k odd
        int p = (2*g + 1) * 256 + tid;
        int k = ((p & 15) << 8) | (p & 240) | (p >> 8);
        int m = k >> 1;
        float2 v = sW[SW(DR11(m))];
        Kh[p] = make_float2((v.x + dD) * s4, v.y * s4);
    }
}

// FFT convolution per (hp, b) on transposed data: contiguous 16-KB row in,
// same row out (in-place, block-private). +D*u and 1/4096 folded into Kf.
__global__ __launch_bounds__(NTH, 5) void k_conv(
    float2* __restrict__ W, const float2* __restrict__ Kf)
{
    __shared__ float2 s[NF];
    const int hp = blockIdx.x;          // hp fast: Kf sharers same XCD
    const int b = blockIdx.y;
    const int tid = threadIdx.x;
    float4* w4 = (float4*)(W + (((size_t)hp * NB + b) << 11));
    #pragma unroll
    for (int i = tid; i < 1024; i += NTH) {
        float4 v = w4[i];
        s[SW(2*i)]   = make_float2(v.x, v.y);
        s[SW(2*i+1)] = make_float2(v.z, v.w);
    }
    __syncthreads();
    // forward DIF 4096 = 16*16*16 (pass 1 exploits zero top half)
    pass16_z(s, tid, 256, -TWO_PI * (float)tid / 4096.f);
    __syncthreads();
    pass16<false>(s, ((tid >> 4) << 8) | (tid & 15), 16,
                  -TWO_PI * (float)(tid & 15) / 256.f);
    __syncthreads();
    pass16<false>(s, tid << 4, 1, 0.f);
    __syncthreads();
    // pointwise in permuted domain
    const float2* K0 = Kf + (size_t)(2 * hp) * NF;
    const float2* K1 = K0 + NF;
    for (int p = tid; p < NF; p += NTH) {
        int k  = ((p & 15) << 8) | (p & 240) | (p >> 8);       // bin at pos p
        int kc = (NF - k) & (NF - 1);
        int pp = ((kc & 15) << 8) | (kc & 240) | (kc >> 8);    // conj bin pos
        if (p > pp) continue;
        if (p == pp) {   // self-conjugate bins (k = 0, 2048)
            float2 X = s[SW(p)];
            float2 g0 = K0[p], g1 = K1[p];
            s[SW(p)] = make_float2(X.x*g0.x - X.y*g1.y, X.x*g0.y + X.y*g1.x);
        } else {
            float2 Xa = s[SW(p)], Xb = s[SW(pp)];
            float2 U0 = make_float2(0.5f*(Xa.x + Xb.x), 0.5f*(Xa.y - Xb.y));
            float2 df = make_float2(Xa.x - Xb.x, Xa.y + Xb.y);
            float2 U1 = make_float2(0.5f*df.y, -0.5f*df.x);
            float2 A0 = K0[p], A1 = K1[p], B0 = K0[pp], B1 = K1[pp];
            float2 y0 = cmul(U0, A0), y1 = cmul(U1, A1);
            s[SW(p)] = make_float2(y0.x - y1.y, y0.y + y1.x);
            float2 U0c = make_float2(U0.x, -U0.y);
            float2 U1c = make_float2(U1.x, -U1.y);
            float2 z0 = cmul(U0c, B0), z1 = cmul(U1c, B1);
            s[SW(pp)] = make_float2(z0.x - z1.y, z0.y + z1.x);
        }
    }
    __syncthreads();
    // inverse DIT 4096 (last pass writes only t<2048)
    pass16<true>(s, tid << 4, 1, 0.f);
    __syncthreads();
    pass16<true>(s, ((tid >> 4) << 8) | (tid & 15), 16,
                 TWO_PI * (float)(tid & 15) / 256.f);
    __syncthreads();
    pass16_li(s, tid, 256, TWO_PI * (float)tid / 4096.f);
    __syncthreads();
    #pragma unroll
    for (int i = tid; i < 1024; i += NTH) {
        float2 a = s[SW(2*i)], c = s[SW(2*i+1)];
        w4[i] = make_float4(a.x, a.y, c.x, c.y);
    }
}

extern "C" void kernel_launch(void* const* d_in, const int* in_sizes, int n_in,
                              void* d_out, int out_size, void* d_ws, size_t ws_size,
                              hipStream_t stream) {
    const float* u   = (const float*)d_in[0];
    const float* Lre = (const float*)d_in[1];
    const float* Lim = (const float*)d_in[2];
    const float* P   = (const float*)d_in[3];
    const float* B   = (const float*)d_in[4];
    const float* C   = (const float*)d_in[5];
    const float* D   = (const float*)d_in[6];
    const float* ls  = (const float*)d_in[7];

    float2* KfP = (float2*)d_ws;                                   // 16.8 MB
    float2* W   = (float2*)((char*)d_ws +
                            (size_t)NH * NF * sizeof(float2));     // 33.6 MB
    float2* Ag  = (float2*)d_out;     // 4.3 MB scratch, overwritten by k_ty

    k_tu    <<<dim3(32, 4, 8), NTH, 0, stream>>>((const float2*)u, W);
    k_cauchy<<<NH * 4, NTH, 0, stream>>>(Lre, Lim, P, B, C, D, ls, Ag, KfP);
    k_kspec <<<NH, NTH, 0, stream>>>(Ag, D, KfP);
    k_conv  <<<dim3(NPAIR, NB), NTH, 0, stream>>>(W, KfP);
    k_ty    <<<dim3(32, 4, 8), NTH, 0, stream>>>(W, (float2*)d_out);
}

// Round 7
// 246.983 us; speedup vs baseline: 1.1439x; 1.0914x over previous
//
#include <hip/hip_runtime.h>
#include <math.h>

#define NTH 256
#define LSEQ 2048
#define NF 4096
#define NH 512
#define NS 64
#define NB 8
#define NPAIR 256
#define ASTR 1040
#define TWO_PI 6.2831853071795864769f
// XOR swizzle: bijective, modifies only bits 0-3; spreads every FFT pass's
// lane pattern evenly over banks.
#define SW(i) ((i) ^ (((i) >> 4) & 15) ^ (((i) >> 8) & 15))
#define DR11(l) ((((l) & 15) << 7) | ((((l) >> 4) & 15) << 3) | ((l) >> 8))
#define PERM12(k) ((((k) & 15) << 8) | ((k) & 240) | ((k) >> 8))

#define C16_1 0.9238795325112867f
#define C16_2 0.7071067811865476f
#define C16_3 0.3826834323650898f

__device__ __forceinline__ float frcp(float x) {
    return __builtin_amdgcn_rcpf(x);
}

__device__ __forceinline__ float2 cmul(float2 a, float2 b) {
    return make_float2(a.x*b.x - a.y*b.y, a.x*b.y + a.y*b.x);
}
__device__ __forceinline__ float2 cmulw(float2 a, float wr, float wi) {
    return make_float2(a.x*wr - a.y*wi, a.x*wi + a.y*wr);
}

// ---- stages 2..4 of the 16-point DIF DFT (shared tail) ----
template<bool INV>
__device__ __forceinline__ void fft16_tail(float2* y) {
    const float sg = INV ? -1.f : 1.f;
    const float WR[8] = {1.f, C16_1, C16_2, C16_3, 0.f, -C16_3, -C16_2, -C16_1};
    const float WI[8] = {0.f, -C16_3, -C16_2, -C16_1, -1.f, -C16_1, -C16_2, -C16_3};
    #pragma unroll
    for (int h = 0; h < 16; h += 8)
        #pragma unroll
        for (int j = 0; j < 4; ++j) {
            float2 a = y[h+j], b = y[h+j+4];
            float2 d = make_float2(a.x-b.x, a.y-b.y);
            y[h+j] = make_float2(a.x+b.x, a.y+b.y);
            y[h+j+4] = cmulw(d, WR[2*j], sg*WI[2*j]);
        }
    #pragma unroll
    for (int h = 0; h < 16; h += 4)
        #pragma unroll
        for (int j = 0; j < 2; ++j) {
            float2 a = y[h+j], b = y[h+j+2];
            float2 d = make_float2(a.x-b.x, a.y-b.y);
            y[h+j] = make_float2(a.x+b.x, a.y+b.y);
            y[h+j+2] = (j == 0) ? d : make_float2(sg*d.y, -sg*d.x);
        }
    #pragma unroll
    for (int h = 0; h < 16; h += 2) {
        float2 a = y[h], b = y[h+1];
        y[h] = make_float2(a.x+b.x, a.y+b.y);
        y[h+1] = make_float2(a.x-b.x, a.y-b.y);
    }
}

// ---- full 16-point DIF DFT. Output: Y[k] = y[rev4[k]]. ----
template<bool INV>
__device__ __forceinline__ void fft16(float2* y) {
    const float sg = INV ? -1.f : 1.f;
    const float WR[8] = {1.f, C16_1, C16_2, C16_3, 0.f, -C16_3, -C16_2, -C16_1};
    const float WI[8] = {0.f, -C16_3, -C16_2, -C16_1, -1.f, -C16_1, -C16_2, -C16_3};
    #pragma unroll
    for (int j = 0; j < 8; ++j) {
        float2 a = y[j], b = y[j+8];
        float2 d = make_float2(a.x-b.x, a.y-b.y);
        y[j] = make_float2(a.x+b.x, a.y+b.y);
        y[j+8] = cmulw(d, WR[j], sg*WI[j]);
    }
    fft16_tail<INV>(y);
}

// ---- 8-point DIF DFT. Output: Y[k] = y[rev3[k]]. ----
template<bool INV>
__device__ __forceinline__ void fft8(float2* y) {
    const float sg = INV ? -1.f : 1.f;
    const float WR[4] = {1.f, C16_2, 0.f, -C16_2};
    const float WI[4] = {0.f, -C16_2, -1.f, -C16_2};
    #pragma unroll
    for (int j = 0; j < 4; ++j) {
        float2 a = y[j], b = y[j+4];
        float2 d = make_float2(a.x-b.x, a.y-b.y);
        y[j] = make_float2(a.x+b.x, a.y+b.y);
        y[j+4] = cmulw(d, WR[j], sg*WI[j]);
    }
    #pragma unroll
    for (int h = 0; h < 8; h += 4)
        #pragma unroll
        for (int j = 0; j < 2; ++j) {
            float2 a = y[h+j], b = y[h+j+2];
            float2 d = make_float2(a.x-b.x, a.y-b.y);
            y[h+j] = make_float2(a.x+b.x, a.y+b.y);
            y[h+j+2] = (j == 0) ? d : make_float2(sg*d.y, -sg*d.x);
        }
    #pragma unroll
    for (int h = 0; h < 8; h += 2) {
        float2 a = y[h], b = y[h+1];
        y[h] = make_float2(a.x+b.x, a.y+b.y);
        y[h+1] = make_float2(a.x-b.x, a.y-b.y);
    }
}

// Radix-16 pass on swizzled LDS. INV=false: DIF forward (natural->DR).
// INV=true: DIT inverse (DR->natural).
template<bool INV>
__device__ __forceinline__ void pass16(float2* s, int base, int str, float ang1) {
    const int rev4[16] = {0,8,4,12,2,10,6,14,1,9,5,13,3,11,7,15};
    float2 y[16];
    float sn, cs;
    __sincosf(ang1, &sn, &cs);
    float2 wb = make_float2(cs, sn);
    if (!INV) {
        #pragma unroll
        for (int j = 0; j < 16; ++j) y[j] = s[SW(base + j*str)];
        fft16<false>(y);
        float2 w = make_float2(1.f, 0.f);
        s[SW(base)] = y[0];
        #pragma unroll
        for (int k = 1; k < 16; ++k) {
            w = cmul(w, wb);
            s[SW(base + k*str)] = cmul(y[rev4[k]], w);
        }
    } else {
        float2 w = make_float2(1.f, 0.f);
        y[0] = s[SW(base)];
        #pragma unroll
        for (int k = 1; k < 16; ++k) {
            w = cmul(w, wb);
            y[k] = cmul(s[SW(base + k*str)], w);
        }
        fft16<true>(y);
        #pragma unroll
        for (int j = 0; j < 16; ++j) s[SW(base + j*str)] = y[rev4[j]];
    }
}

// Forward radix-16 pass with implicit-zero top half (j>=8 inputs are zero).
__device__ __forceinline__ void pass16_z(float2* s, int base, int str, float ang1) {
    const int rev4[16] = {0,8,4,12,2,10,6,14,1,9,5,13,3,11,7,15};
    const float WR[8] = {1.f, C16_1, C16_2, C16_3, 0.f, -C16_3, -C16_2, -C16_1};
    const float WI[8] = {0.f, -C16_3, -C16_2, -C16_1, -1.f, -C16_1, -C16_2, -C16_3};
    float2 y[16];
    float sn, cs;
    __sincosf(ang1, &sn, &cs);
    float2 wb = make_float2(cs, sn);
    #pragma unroll
    for (int j = 0; j < 8; ++j) y[j] = s[SW(base + j*str)];
    #pragma unroll
    for (int j = 0; j < 8; ++j) y[j+8] = cmulw(y[j], WR[j], WI[j]);
    fft16_tail<false>(y);
    float2 w = make_float2(1.f, 0.f);
    s[SW(base)] = y[0];
    #pragma unroll
    for (int k = 1; k < 16; ++k) {
        w = cmul(w, wb);
        s[SW(base + k*str)] = cmul(y[rev4[k]], w);
    }
}

// Final inverse radix-16 pass: only j<8 outputs (t<2048) are needed.
__device__ __forceinline__ void pass16_li(float2* s, int base, int str, float ang1) {
    const int rev4[16] = {0,8,4,12,2,10,6,14,1,9,5,13,3,11,7,15};
    float2 y[16];
    float sn, cs;
    __sincosf(ang1, &sn, &cs);
    float2 wb = make_float2(cs, sn);
    float2 w = make_float2(1.f, 0.f);
    y[0] = s[SW(base)];
    #pragma unroll
    for (int k = 1; k < 16; ++k) {
        w = cmul(w, wb);
        y[k] = cmul(s[SW(base + k*str)], w);
    }
    fft16<true>(y);
    #pragma unroll
    for (int j = 0; j < 8; ++j) s[SW(base + j*str)] = y[rev4[j]];
}

template<bool INV>
__device__ __forceinline__ void pass8(float2* s, int base, int str, float ang1) {
    const int rev3[8] = {0,4,2,6,1,5,3,7};
    float2 y[8];
    float sn, cs;
    __sincosf(ang1, &sn, &cs);
    float2 wb = make_float2(cs, sn);
    if (!INV) {
        #pragma unroll
        for (int j = 0; j < 8; ++j) y[j] = s[SW(base + j*str)];
        fft8<false>(y);
        float2 w = make_float2(1.f, 0.f);
        s[SW(base)] = y[0];
        #pragma unroll
        for (int k = 1; k < 8; ++k) {
            w = cmul(w, wb);
            s[SW(base + k*str)] = cmul(y[rev3[k]], w);
        }
    } else {
        float2 w = make_float2(1.f, 0.f);
        y[0] = s[SW(base)];
        #pragma unroll
        for (int k = 1; k < 8; ++k) {
            w = cmul(w, wb);
            y[k] = cmul(s[SW(base + k*str)], w);
        }
        fft8<true>(y);
        #pragma unroll
        for (int j = 0; j < 8; ++j) s[SW(base + j*str)] = y[rev3[j]];
    }
}

// Transpose u [b][t][hp]f2 -> W [hp][b][t]f2 via 64x64 LDS tiles.
__global__ __launch_bounds__(NTH) void k_tu(
    const float2* __restrict__ u2, float2* __restrict__ W)
{
    __shared__ float2 tile[64][65];
    const int t0 = blockIdx.x * 64, hp0 = blockIdx.y * 64, b = blockIdx.z;
    const int tx = threadIdx.x & 63, ty = threadIdx.x >> 6;
    #pragma unroll
    for (int r = 0; r < 64; r += 4)
        tile[r + ty][tx] = u2[((size_t)b * LSEQ + t0 + r + ty) * NPAIR + hp0 + tx];
    __syncthreads();
    #pragma unroll
    for (int r = 0; r < 64; r += 4)
        W[(((size_t)(hp0 + r + ty) * NB + b) << 11) + t0 + tx] = tile[tx][r + ty];
}

// Transpose W [hp][b][t]f2 -> out [b][t][hp]f2.
__global__ __launch_bounds__(NTH) void k_ty(
    const float2* __restrict__ W, float2* __restrict__ out2)
{
    __shared__ float2 tile[64][65];
    const int t0 = blockIdx.x * 64, hp0 = blockIdx.y * 64, b = blockIdx.z;
    const int tx = threadIdx.x & 63, ty = threadIdx.x >> 6;
    #pragma unroll
    for (int r = 0; r < 64; r += 4)   // tile[hp_local][t_local]
        tile[r + ty][tx] = W[(((size_t)(hp0 + r + ty) * NB + b) << 11) + t0 + tx];
    __syncthreads();
    #pragma unroll
    for (int r = 0; r < 64; r += 4)
        out2[((size_t)b * LSEQ + t0 + r + ty) * NPAIR + hp0 + tx] = tile[tx][r + ty];
}

// Cauchy evaluation: 8 blocks per head, ONE frequency per thread.
// tid<128: l = q*128+tid; tid>=128: mirror l' = 2048-(q*128+(tid-128)).
// Pairs combined via LDS; A[0..1024) written coalesced; even Kf bins
// (dr12-permuted positions) scattered. All rcp via v_rcp_f32 (1 ulp).
__global__ __launch_bounds__(NTH, 4) void k_cauchy(
    const float* __restrict__ Lre, const float* __restrict__ Lim,
    const float* __restrict__ Pm, const float* __restrict__ Bm,
    const float* __restrict__ Cm, const float* __restrict__ Dp,
    const float* __restrict__ logstep,
    float2* __restrict__ Ag, float2* __restrict__ KfP)
{
    __shared__ float4 cA[NS];   // dre, dre^2, lam_im, |P|^2
    __shared__ float4 cB[NS];   // conj(C)B, conj(C)P
    __shared__ float2 cC[NS];   // conj(P)B
    __shared__ float shx[NTH], shy[NTH];
    const int h = blockIdx.x >> 3;
    const int q = blockIdx.x & 7;
    const int tid = threadIdx.x;
    if (tid < NS) {
        int i = h * NS + tid;
        float Lx = fminf(Lre[i], -1e-4f), Ly = Lim[i];
        float Px = Pm[2*i], Py = Pm[2*i+1];
        float Bx = Bm[2*i], By = Bm[2*i+1];
        float Cx = Cm[2*i], Cy = Cm[2*i+1];
        float dre = -Lx;
        cA[tid] = make_float4(dre, dre*dre, Ly, Px*Px + Py*Py);
        cB[tid] = make_float4(Cx*Bx + Cy*By, Cx*By - Cy*Bx,
                              Cx*Px + Cy*Py, Cx*Py - Cy*Px);
        cC[tid] = make_float2(Px*Bx + Py*By, Px*By - Py*Bx);
    }
    __syncthreads();
    const float step = expf(logstep[h]);
    const float a2s = 2.0f / step;
    // this thread's frequency (mirror pair sits at tid^128's slot)
    const int l = (tid < 128) ? (q * 128 + tid)
                              : (LSEQ - (q * 128 + (tid - 128)));
    float r = (float)l * (1.0f / (float)LSEQ);
    float tg = sinpif(r) * frcp(cospif(r));      // tan(pi*l/L)
    float g1 = a2s * tg;
    float s0=0,s1=0,s2=0,s3=0,s4a=0,s5=0,s6=0,s7=0;
    #pragma unroll 4
    for (int n = 0; n < NS; ++n) {
        float4 ca = cA[n];
        float4 cb = cB[n];
        float2 cc = cC[n];
        float di = g1 - ca.z;
        float iv = frcp(fmaf(di, di, ca.y));
        float rx = ca.x * iv, ry = di * iv;      // rec = rx - i*ry
        s0 += cb.x*rx + cb.y*ry;  s1 += cb.y*rx - cb.x*ry;
        s2 += cb.z*rx + cb.w*ry;  s3 += cb.w*rx - cb.z*ry;
        s4a += cc.x*rx + cc.y*ry; s5 += cc.y*rx - cc.x*ry;
        s6 += ca.w*rx;            s7 -= ca.w*ry;
    }
    // finalize: (1 + i*tg) * (s00 - s01*s10/(1+s11))
    float denx = 1.0f + s6, deny = s7;
    float dinv = frcp(denx*denx + deny*deny);
    float numx = s2*s4a - s3*s5;
    float numy = s2*s5 + s3*s4a;
    float qx = (numx*denx + numy*deny) * dinv;
    float qy = (numy*denx - numx*deny) * dinv;
    float kx = s0 - qx, ky = s1 - qy;
    float arx = kx - tg*ky, ary = ky + tg*kx;
    shx[tid] = arx; shy[tid] = ary;
    __syncthreads();
    const float dD = Dp[h];
    const float sc4 = 1.0f / (float)NF;
    float2* Kh = KfP + (size_t)h * NF;
    if (tid < 128) {
        // A[l] = (at[l] + conj(at[2048-l]))/2
        float2 A = make_float2(0.5f*(arx + shx[tid + 128]),
                               0.5f*(ary - shy[tid + 128]));
        Ag[(size_t)h * ASTR + l] = A;
        int k1 = 2 * l;
        Kh[PERM12(k1)] = make_float2((A.x + dD)*sc4, A.y*sc4);
        int k2 = (NF - k1) & (NF - 1);
        Kh[PERM12(k2)] = make_float2((A.x + dD)*sc4, -A.y*sc4);
    }
    if (q == 0 && tid == 0) {
        // l = 1024: tan -> inf limit, A[1024] = Re((step/2)*sum(conj(C)B))
        float sx = 0.f;
        for (int n = 0; n < NS; ++n) sx += cB[n].x;
        float2 Am = make_float2(0.5f * step * sx, 0.f);
        Ag[(size_t)h * ASTR + 1024] = Am;
        Kh[8] = make_float2((Am.x + dD) * sc4, 0.f);  // bin 2048 -> pos 8
    }
}

// Odd Kf bins: one head per block (512 blocks, 16 KB LDS).
// IDIT-2048(A) -> K -> modulate e^{-2pi i t/4096} -> DIF-2048 -> odd bins.
__global__ __launch_bounds__(NTH) void k_kspec(
    const float2* __restrict__ Ag, const float* __restrict__ Dp,
    float2* __restrict__ KfP)
{
    __shared__ float2 sW[LSEQ];
    const int h = blockIdx.x;
    const int tid = threadIdx.x;
    const float2* Ah = Ag + (size_t)h * ASTR;
    for (int l = tid; l <= LSEQ/2; l += NTH) {
        float2 A = Ah[l];
        sW[SW(DR11(l))] = A;
        if (l > 0 && l < LSEQ/2)
            sW[SW(DR11(LSEQ - l))] = make_float2(A.x, -A.y);
    }
    __syncthreads();
    // inverse DIT-2048 (DR -> natural time)
    pass8<true>(sW, tid << 3, 1, 0.f);
    __syncthreads();
    if (tid < 128) pass16<true>(sW, ((tid >> 3) << 7) | (tid & 7), 8,
                                TWO_PI * (float)(tid & 7) / 128.f);
    __syncthreads();
    if (tid < 128) pass16<true>(sW, tid, 128, TWO_PI * (float)tid / 2048.f);
    __syncthreads();
    // modulate: K[t]/2048 * e^{-2pi i t/4096}
    for (int t = tid; t < LSEQ; t += NTH) {
        float kv = sW[SW(t)].x * (1.0f / (float)LSEQ);
        float sn, cs;
        __sincosf(-TWO_PI * (float)t / (float)NF, &sn, &cs);
        sW[SW(t)] = make_float2(kv * cs, kv * sn);
    }
    __syncthreads();
    // forward DIF-2048 (natural -> DR spectrum)
    if (tid < 128) pass16<false>(sW, tid, 128, -TWO_PI * (float)tid / 2048.f);
    __syncthreads();
    if (tid < 128) pass16<false>(sW, ((tid >> 3) << 7) | (tid & 7), 8,
                                 -TWO_PI * (float)(tid & 7) / 128.f);
    __syncthreads();
    pass8<false>(sW, tid << 3, 1, 0.f);
    __syncthreads();
    const float dD = Dp[h];
    const float s4 = 1.0f / (float)NF;
    float2* Kh = KfP + (size_t)h * NF;
    #pragma unroll
    for (int g = 0; g < 8; ++g) {      // positions with (p>>8) odd <=> k odd
        int p = (2*g + 1) * 256 + tid;
        int k = ((p & 15) << 8) | (p & 240) | (p >> 8);
        int m = k >> 1;
        float2 v = sW[SW(DR11(m))];
        Kh[p] = make_float2((v.x + dD) * s4, v.y * s4);
    }
}

// FFT convolution per (hp, b) on transposed data: contiguous 16-KB row in,
// same row out (in-place, block-private). +D*u and 1/4096 folded into Kf.
// Grid: idx = 8*(b + 8*(hp>>3)) + (hp&7) -> b-siblings of one hp adjacent
// in dispatch AND on one XCD (idx%8 = hp&7): Kf row read once per XCD.
__global__ __launch_bounds__(NTH, 5) void k_conv(
    float2* __restrict__ W, const float2* __restrict__ Kf)
{
    __shared__ float2 s[NF];
    const int idx = blockIdx.x;
    const int b  = (idx >> 3) & 7;
    const int hp = ((idx >> 6) << 3) | (idx & 7);
    const int tid = threadIdx.x;
    float4* w4 = (float4*)(W + (((size_t)hp * NB + b) << 11));
    for (int i = tid; i < 1024; i += NTH) {
        float4 v = w4[i];
        s[SW(2*i)]   = make_float2(v.x, v.y);
        s[SW(2*i+1)] = make_float2(v.z, v.w);
    }
    __syncthreads();
    // forward DIF 4096 = 16*16*16 (pass 1 exploits zero top half)
    pass16_z(s, tid, 256, -TWO_PI * (float)tid / 4096.f);
    __syncthreads();
    pass16<false>(s, ((tid >> 4) << 8) | (tid & 15), 16,
                  -TWO_PI * (float)(tid & 15) / 256.f);
    __syncthreads();
    pass16<false>(s, tid << 4, 1, 0.f);
    __syncthreads();
    // pointwise in permuted domain
    const float2* K0 = Kf + (size_t)(2 * hp) * NF;
    const float2* K1 = K0 + NF;
    for (int p = tid; p < NF; p += NTH) {
        int k  = ((p & 15) << 8) | (p & 240) | (p >> 8);       // bin at pos p
        int kc = (NF - k) & (NF - 1);
        int pp = ((kc & 15) << 8) | (kc & 240) | (kc >> 8);    // conj bin pos
        if (p > pp) continue;
        if (p == pp) {   // self-conjugate bins (k = 0, 2048)
            float2 X = s[SW(p)];
            float2 g0 = K0[p], g1 = K1[p];
            s[SW(p)] = make_float2(X.x*g0.x - X.y*g1.y, X.x*g0.y + X.y*g1.x);
        } else {
            float2 Xa = s[SW(p)], Xb = s[SW(pp)];
            float2 U0 = make_float2(0.5f*(Xa.x + Xb.x), 0.5f*(Xa.y - Xb.y));
            float2 df = make_float2(Xa.x - Xb.x, Xa.y + Xb.y);
            float2 U1 = make_float2(0.5f*df.y, -0.5f*df.x);
            float2 A0 = K0[p], A1 = K1[p], B0 = K0[pp], B1 = K1[pp];
            float2 y0 = cmul(U0, A0), y1 = cmul(U1, A1);
            s[SW(p)] = make_float2(y0.x - y1.y, y0.y + y1.x);
            float2 U0c = make_float2(U0.x, -U0.y);
            float2 U1c = make_float2(U1.x, -U1.y);
            float2 z0 = cmul(U0c, B0), z1 = cmul(U1c, B1);
            s[SW(pp)] = make_float2(z0.x - z1.y, z0.y + z1.x);
        }
    }
    __syncthreads();
    // inverse DIT 4096 (last pass writes only t<2048)
    pass16<true>(s, tid << 4, 1, 0.f);
    __syncthreads();
    pass16<true>(s, ((tid >> 4) << 8) | (tid & 15), 16,
                 TWO_PI * (float)(tid & 15) / 256.f);
    __syncthreads();
    pass16_li(s, tid, 256, TWO_PI * (float)tid / 4096.f);
    __syncthreads();
    for (int i = tid; i < 1024; i += NTH) {
        float2 a = s[SW(2*i)], c = s[SW(2*i+1)];
        w4[i] = make_float4(a.x, a.y, c.x, c.y);
    }
}

extern "C" void kernel_launch(void* const* d_in, const int* in_sizes, int n_in,
                              void* d_out, int out_size, void* d_ws, size_t ws_size,
                              hipStream_t stream) {
    const float* u   = (const float*)d_in[0];
    const float* Lre = (const float*)d_in[1];
    const float* Lim = (const float*)d_in[2];
    const float* P   = (const float*)d_in[3];
    const float* B   = (const float*)d_in[4];
    const float* C   = (const float*)d_in[5];
    const float* D   = (const float*)d_in[6];
    const float* ls  = (const float*)d_in[7];

    float2* KfP = (float2*)d_ws;                                   // 16.8 MB
    float2* W   = (float2*)((char*)d_ws +
                            (size_t)NH * NF * sizeof(float2));     // 33.6 MB
    float2* Ag  = (float2*)d_out;     // 4.3 MB scratch, overwritten by k_ty

    k_tu    <<<dim3(32, 4, 8), NTH, 0, stream>>>((const float2*)u, W);
    k_cauchy<<<NH * 8, NTH, 0, stream>>>(Lre, Lim, P, B, C, D, ls, Ag, KfP);
    k_kspec <<<NH, NTH, 0, stream>>>(Ag, D, KfP);
    k_conv  <<<NPAIR * NB, NTH, 0, stream>>>(W, KfP);
    k_ty    <<<dim3(32, 4, 8), NTH, 0, stream>>>(W, (float2*)d_out);
}